// Round 7
// baseline (240.930 us; speedup 1.0000x reference)
//
#include <hip/hip_runtime.h>
#include <math.h>

#define D_MODEL 512
#define NHEAD   8
#define HD      64
#define T_SEQ   2048
#define BATCH   4
#define M_ROWS  (BATCH * T_SEQ)   // 8192

typedef __attribute__((ext_vector_type(8))) short  short8;   // 8 bf16 = 4 VGPRs
typedef __attribute__((ext_vector_type(4))) float  floatx4;

// round-to-nearest-even fp32 -> bf16 (bit math; inputs finite)
__device__ __forceinline__ unsigned short f2bf(float f) {
    unsigned int u = __float_as_uint(f);
    unsigned int r = u + 0x7FFFu + ((u >> 16) & 1u);
    return (unsigned short)(r >> 16);
}

// ---------------------------------------------------------------------------
// Kernel 0: all fp32 -> bf16 conversions in one launch (x, in_w, out_w).
// ---------------------------------------------------------------------------
#define N8_X  (M_ROWS * D_MODEL / 8)                 // 524288
#define N8_W1 (3 * D_MODEL * D_MODEL / 8)            // 98304
#define N8_W2 (D_MODEL * D_MODEL / 8)                // 32768

__global__ __launch_bounds__(256) void cvt_all(
    const float* __restrict__ x,  const float* __restrict__ w1,
    const float* __restrict__ w2,
    unsigned short* __restrict__ xb, unsigned short* __restrict__ w1b,
    unsigned short* __restrict__ w2b)
{
    int idx = blockIdx.x * 256 + threadIdx.x;
    const float* src; unsigned short* dst;
    if (idx < N8_X)               { src = x;  dst = xb;  }
    else if (idx < N8_X + N8_W1)  { idx -= N8_X;          src = w1; dst = w1b; }
    else                          { idx -= (N8_X + N8_W1); src = w2; dst = w2b; }
    const float4 a = ((const float4*)src)[idx * 2];
    const float4 b = ((const float4*)src)[idx * 2 + 1];
    ushort4 lo, hi;
    lo.x = f2bf(a.x); lo.y = f2bf(a.y); lo.z = f2bf(a.z); lo.w = f2bf(a.w);
    hi.x = f2bf(b.x); hi.y = f2bf(b.y); hi.z = f2bf(b.z); hi.w = f2bf(b.w);
    ((ushort4*)dst)[idx * 2]     = lo;
    ((ushort4*)dst)[idx * 2 + 1] = hi;
}

// ---------------------------------------------------------------------------
// Kernel 1: QKV projection, bf16 MFMA; emits q/k/v as bf16 head-major.
// Staging registers are software-pipelined one K-iteration ahead so global
// load latency overlaps the MFMA phase instead of the barrier.
// ---------------------------------------------------------------------------
__global__ __launch_bounds__(256) void qkv_gemm_mfma(
    const unsigned short* __restrict__ A,   // 8192 x 512 bf16
    const unsigned short* __restrict__ W,   // 1536 x 512 bf16
    const float* __restrict__ bias,
    unsigned short* __restrict__ qo, unsigned short* __restrict__ ko,
    unsigned short* __restrict__ vo)
{
    __shared__ unsigned short smem[128 * 128];    // 32 KB: As|Bs, then C-tile
    unsigned short* const As = smem;              // 128 x 64
    unsigned short* const Bs = smem + 128 * 64;   // 128 x 64

    const int bid  = blockIdx.x;
    const int xcd  = bid & 7;
    const int chk_ = bid >> 3;                            // 0..95
    const int row0 = (((chk_ / 12) << 3) + xcd) << 7;     // row-tile * 128
    const int col0 = (chk_ % 12) << 7;                    // col-tile * 128

    const int tid  = threadIdx.x;
    const int wave = tid >> 6, lane = tid & 63;
    const int quad = lane >> 4, l15 = lane & 15;
    const int wm   = wave >> 1, wn = wave & 1;
    const int lr8  = lane >> 3;       // staging: row-within-8
    const int sc   = lane & 7;        // staging: 16B chunk 0..7

    floatx4 acc[4][4] = {};

    int4 av[4], bv[4];
#pragma unroll
    for (int i = 0; i < 4; ++i) {
        const int r = wave * 32 + i * 8 + lr8;
        av[i] = *(const int4*)(A + ((size_t)(row0 + r) << 9) + (sc << 3));
        bv[i] = *(const int4*)(W + ((size_t)(col0 + r) << 9) + (sc << 3));
    }

    for (int k0 = 0; k0 < D_MODEL; k0 += 64) {
        __syncthreads();
#pragma unroll
        for (int i = 0; i < 4; ++i) {
            const int r  = wave * 32 + i * 8 + lr8;
            const int cp = (sc ^ (r & 7)) << 3;
            *(int4*)(As + (r << 6) + cp) = av[i];
            *(int4*)(Bs + (r << 6) + cp) = bv[i];
        }
        __syncthreads();

        // prefetch next K-slab while MFMAs run
        if (k0 + 64 < D_MODEL) {
#pragma unroll
            for (int i = 0; i < 4; ++i) {
                const int r = wave * 32 + i * 8 + lr8;
                av[i] = *(const int4*)(A + ((size_t)(row0 + r) << 9) + k0 + 64 + (sc << 3));
                bv[i] = *(const int4*)(W + ((size_t)(col0 + r) << 9) + k0 + 64 + (sc << 3));
            }
        }

#pragma unroll
        for (int ks = 0; ks < 2; ++ks) {
            short8 af[4], bfr[4];
            const int ch = (ks << 2) + quad;
#pragma unroll
            for (int mt = 0; mt < 4; ++mt) {
                const int row = (wm << 6) + (mt << 4) + l15;
                af[mt] = *(const short8*)(As + (row << 6) + ((ch ^ (row & 7)) << 3));
            }
#pragma unroll
            for (int nt = 0; nt < 4; ++nt) {
                const int col = (wn << 6) + (nt << 4) + l15;
                bfr[nt] = *(const short8*)(Bs + (col << 6) + ((ch ^ (col & 7)) << 3));
            }
#pragma unroll
            for (int mt = 0; mt < 4; ++mt)
#pragma unroll
                for (int nt = 0; nt < 4; ++nt)
                    acc[mt][nt] = __builtin_amdgcn_mfma_f32_16x16x32_bf16(
                        af[mt], bfr[nt], acc[mt][nt], 0, 0, 0);
        }
    }

    // ---- epilogue: bias + bf16 -> LDS 128x128, then full-line stores ----
    __syncthreads();          // all waves done with As/Bs fragments
#pragma unroll
    for (int nt = 0; nt < 4; ++nt) {
        const int ncol = (wn << 6) + (nt << 4) + l15;
        const float bn = bias[col0 + ncol];
#pragma unroll
        for (int mt = 0; mt < 4; ++mt)
#pragma unroll
            for (int reg = 0; reg < 4; ++reg) {
                const int mrow = (wm << 6) + (mt << 4) + (quad << 2) + reg;
                smem[(mrow << 7) + ncol] = f2bf(acc[mt][nt][reg] + bn);
            }
    }
    __syncthreads();
    {
        const int c16  = lane & 15;            // 16-B chunk 0..15 (128 cols)
        const int rsub = lane >> 4;            // row-within-4
        const int n0   = col0 + (c16 << 3);
        const int part = n0 >> 9;
        unsigned short* dst = (part == 0) ? qo : ((part == 1) ? ko : vo);
        const int head = (n0 & 511) >> 6, d0 = n0 & 63;
#pragma unroll
        for (int p = 0; p < 8; ++p) {
            const int ml = (wave << 5) + (p << 2) + rsub;   // 0..127
            const int m  = row0 + ml;
            const int b = m >> 11, t = m & 2047;
            int4 val = *(const int4*)(smem + (ml << 7) + (c16 << 3));
            *(int4*)(dst + ((((size_t)b << 3) + head) * T_SEQ + t) * HD + d0) = val;
        }
    }
}

// ---------------------------------------------------------------------------
// Kernel 2: residue-class flash attention, bf16 MFMA.
// Softmax: wave-wide TILE max (6 shuffles; exact — any bound >= row max
// works, score spread ~±10 so no underflow) + row sums via 2 extra MFMA
// with a ones B-fragment (l-update read from C-layout regs).
// ---------------------------------------------------------------------------
__global__ __launch_bounds__(256) void attn_rc_mfma(
    const unsigned short* __restrict__ q, const unsigned short* __restrict__ k,
    const unsigned short* __restrict__ v, const int* __restrict__ periods,
    unsigned short* __restrict__ o)
{
    __shared__ unsigned short Ks[64 * 64];   // [key][hd]; O-tile in epilogue
    __shared__ unsigned short Vt[64 * 64];   // [hd][key]
    __shared__ unsigned short Ps[64 * 64];   // Q tile, then P̃ [q][key]

    const int bh = blockIdx.y;
    int P = periods[bh]; if (P < 1) P = 1;
    const int q0 = T_SEQ / P, rem = T_SEQ % P;
    const int nt_hi = (q0 + 64) >> 6;
    const int nt_lo = (q0 + 63) >> 6;
    int t = blockIdx.x;
    int r, mt, Lr;
    const int hi_total = rem * nt_hi;
    if (t < hi_total) {
        r = t / nt_hi; mt = t - r * nt_hi; Lr = q0 + 1;
    } else {
        t -= hi_total;
        if (t >= (P - rem) * nt_lo) return;
        const int rr = t / nt_lo;
        r = rem + rr; mt = t - rr * nt_lo; Lr = q0;
    }
    const int m0 = mt << 6;

    const int tid  = threadIdx.x;
    const int wave = tid >> 6, lane = tid & 63;
    const int quad = lane >> 4, l15 = lane & 15;
    const int srow = tid >> 2;                 // K/Q staging row 0..63
    const int vkp  = tid & 31, vhg = tid >> 5; // V staging

    const unsigned short* hq = q + (size_t)bh * T_SEQ * HD;
    const unsigned short* hk = k + (size_t)bh * T_SEQ * HD;
    const unsigned short* hv = v + (size_t)bh * T_SEQ * HD;

    const short8 vone = {16256, 16256, 16256, 16256,
                         16256, 16256, 16256, 16256};   // bf16 1.0 x8

    // ---- stage Q tile into Ps, pull A-frags to regs ----
    {
        int m = m0 + srow; if (m > Lr - 1) m = Lr - 1;
        const unsigned short* src = hq + (size_t)(r + m * P) * HD;
#pragma unroll
        for (int rep = 0; rep < 2; ++rep) {
            const int c = ((tid & 3) << 1) + rep;
            int4 a = *(const int4*)(src + (c << 3));
            *(int4*)(Ps + (srow << 6) + ((c ^ (srow & 7)) << 3)) = a;
        }
    }
    __syncthreads();
    short8 qf[2];
#pragma unroll
    for (int ks = 0; ks < 2; ++ks) {
        const int row = (wave << 4) + l15;
        qf[ks] = *(const short8*)(Ps + (row << 6) +
                                  ((((ks << 2) + quad) ^ (row & 7)) << 3));
    }

    floatx4 Oa[4] = {};
    float m_i[4] = {-1e30f, -1e30f, -1e30f, -1e30f};
    float l_i[4] = {0.f, 0.f, 0.f, 0.f};

    for (int kt = 0; kt <= mt; ++kt) {
        const int km0 = kt << 6;

        int mk = km0 + srow; if (mk > Lr - 1) mk = Lr - 1;
        const unsigned short* ksrc = hk + (size_t)(r + mk * P) * HD;
        int4 ka[2];
#pragma unroll
        for (int rep = 0; rep < 2; ++rep)
            ka[rep] = *(const int4*)(ksrc + ((((tid & 3) << 1) + rep) << 3));
        int mv0 = km0 + (vkp << 1);     if (mv0 > Lr - 1) mv0 = Lr - 1;
        int mv1 = km0 + (vkp << 1) + 1; if (mv1 > Lr - 1) mv1 = Lr - 1;
        int4 va = *(const int4*)(hv + (size_t)(r + mv0 * P) * HD + (vhg << 3));
        int4 vb = *(const int4*)(hv + (size_t)(r + mv1 * P) * HD + (vhg << 3));

        __syncthreads();

#pragma unroll
        for (int rep = 0; rep < 2; ++rep) {
            const int c = ((tid & 3) << 1) + rep;
            *(int4*)(Ks + (srow << 6) + ((c ^ (srow & 7)) << 3)) = ka[rep];
        }
        {
            const unsigned short* pa = (const unsigned short*)&va;
            const unsigned short* pb = (const unsigned short*)&vb;
#pragma unroll
            for (int j = 0; j < 8; ++j) {
                const int hd_ = (vhg << 3) + j;
                const unsigned int pk =
                    (unsigned int)pa[j] | ((unsigned int)pb[j] << 16);
                *(unsigned int*)((char*)Vt + (hd_ << 7) +
                                 ((((vkp >> 2) ^ (hd_ & 7)) << 4)) +
                                 ((vkp & 3) << 2)) = pk;
            }
        }
        __syncthreads();

        // ---- QK^T ----
        floatx4 sacc[4] = {};
#pragma unroll
        for (int nt = 0; nt < 4; ++nt) {
            const int row = (nt << 4) + l15;
#pragma unroll
            for (int ks = 0; ks < 2; ++ks) {
                short8 kf = *(const short8*)(Ks + (row << 6) +
                                             ((((ks << 2) + quad) ^ (row & 7)) << 3));
                sacc[nt] = __builtin_amdgcn_mfma_f32_16x16x32_bf16(
                    qf[ks], kf, sacc[nt], 0, 0, 0);
            }
        }

        // ---- scale + causal mask; wave-wide tile max ----
        const bool diag = (kt == mt);
        float s[4][4];                        // [nt][reg]
        float tm = -1e30f;
#pragma unroll
        for (int nt = 0; nt < 4; ++nt)
#pragma unroll
            for (int reg = 0; reg < 4; ++reg) {
                float sv = sacc[nt][reg] * 0.125f;
                if (diag) {
                    const int sq = (wave << 4) + (quad << 2) + reg;
                    if (((nt << 4) + l15) > sq) sv = -1e30f;
                }
                s[nt][reg] = sv;
                tm = fmaxf(tm, sv);
            }
        tm = fmaxf(tm, __shfl_xor(tm, 1));
        tm = fmaxf(tm, __shfl_xor(tm, 2));
        tm = fmaxf(tm, __shfl_xor(tm, 4));
        tm = fmaxf(tm, __shfl_xor(tm, 8));
        tm = fmaxf(tm, __shfl_xor(tm, 16));
        tm = fmaxf(tm, __shfl_xor(tm, 32));

        float sc[4];
#pragma unroll
        for (int reg = 0; reg < 4; ++reg) {
            const float nm = fmaxf(m_i[reg], tm);
            sc[reg] = __expf(m_i[reg] - nm);
            m_i[reg] = nm;
        }

        // ---- P̃ -> Ps [q][key] bf16 (own-wave rows only) ----
#pragma unroll
        for (int reg = 0; reg < 4; ++reg) {
            const int row = (wave << 4) + (quad << 2) + reg;
#pragma unroll
            for (int nt = 0; nt < 4; ++nt) {
                const int col = (nt << 4) + l15;
                *((unsigned short*)((char*)Ps + (row << 7) +
                                    (((col >> 3) ^ (row & 7)) << 4) +
                                    ((col & 7) << 1))) =
                    f2bf(__expf(s[nt][reg] - m_i[reg]));
            }
        }

        // ---- read P̃ A-frags; row sums via MFMA(ones); l update ----
        short8 pf[2];
#pragma unroll
        for (int ks = 0; ks < 2; ++ks) {
            const int row = (wave << 4) + l15;
            pf[ks] = *(const short8*)(Ps + (row << 6) +
                                      ((((ks << 2) + quad) ^ (row & 7)) << 3));
        }
        floatx4 ls = {};
        ls = __builtin_amdgcn_mfma_f32_16x16x32_bf16(pf[0], vone, ls, 0, 0, 0);
        ls = __builtin_amdgcn_mfma_f32_16x16x32_bf16(pf[1], vone, ls, 0, 0, 0);
#pragma unroll
        for (int reg = 0; reg < 4; ++reg)
            l_i[reg] = l_i[reg] * sc[reg] + ls[reg];

        // ---- PV ----
#pragma unroll
        for (int nt = 0; nt < 4; ++nt)
#pragma unroll
            for (int reg = 0; reg < 4; ++reg)
                Oa[nt][reg] *= sc[reg];
#pragma unroll
        for (int nt = 0; nt < 4; ++nt) {
            const int row = (nt << 4) + l15;
#pragma unroll
            for (int ks = 0; ks < 2; ++ks) {
                short8 vf = *(const short8*)(Vt + (row << 6) +
                                             ((((ks << 2) + quad) ^ (row & 7)) << 3));
                Oa[nt] = __builtin_amdgcn_mfma_f32_16x16x32_bf16(
                    pf[ks], vf, Oa[nt], 0, 0, 0);
            }
        }
    }

    // ---- epilogue: O through LDS (Ks dead), full-line stores ----
    __syncthreads();          // all waves done reading Ks/Vt
#pragma unroll
    for (int reg = 0; reg < 4; ++reg) {
        const float invl = 1.f / l_i[reg];
        const int row = (wave << 4) + (quad << 2) + reg;
#pragma unroll
        for (int nt = 0; nt < 4; ++nt)
            Ks[(row << 6) + (nt << 4) + l15] = f2bf(Oa[nt][reg] * invl);
    }
    {
        const int lrow = lane >> 2;
        const int chk  = (lane & 3) << 1;
        const int ml   = (wave << 4) + lrow;
        const int m    = m0 + ml;
        if (m < Lr) {
            const size_t base = ((size_t)bh * T_SEQ + (r + m * P)) * HD;
            int4 w0 = *(const int4*)(Ks + (ml << 6) + (chk << 3));
            int4 w1 = *(const int4*)(Ks + (ml << 6) + ((chk + 1) << 3));
            *(int4*)(o + base + (chk << 3))       = w0;
            *(int4*)(o + base + ((chk + 1) << 3)) = w1;
        }
    }
}

// ---------------------------------------------------------------------------
// Kernel 3: out projection, bf16 MFMA (A head-major (B,H,T,64) bf16),
// staging software-pipelined like qkv.
// ---------------------------------------------------------------------------
__global__ __launch_bounds__(256) void out_gemm_mfma(
    const unsigned short* __restrict__ A,
    const unsigned short* __restrict__ W,   // 512 x 512 bf16
    const float* __restrict__ bias,
    float* __restrict__ out)
{
    __shared__ unsigned short As[128 * 64];
    __shared__ unsigned short Bs[128 * 64];

    const int tid  = threadIdx.x;
    const int wave = tid >> 6, lane = tid & 63;
    const int quad = lane >> 4, l15 = lane & 15;
    const int wm   = wave >> 1, wn = wave & 1;
    const int row0 = blockIdx.x * 128;
    const int col0 = blockIdx.y * 128;
    const int lr8  = lane >> 3;
    const int sc   = lane & 7;

    floatx4 acc[4][4] = {};

    int4 av[4], bv[4];
#pragma unroll
    for (int i = 0; i < 4; ++i) {
        const int r  = wave * 32 + i * 8 + lr8;
        const int rg = row0 + r;
        const int b = rg >> 11, t = rg & 2047;
        av[i] = *(const int4*)(A + ((((size_t)b << 3) + 0) * T_SEQ + t) * HD + (sc << 3));
        bv[i] = *(const int4*)(W + ((size_t)(col0 + r) << 9) + (sc << 3));
    }

    for (int k0 = 0; k0 < D_MODEL; k0 += 64) {
        __syncthreads();
#pragma unroll
        for (int i = 0; i < 4; ++i) {
            const int r  = wave * 32 + i * 8 + lr8;
            const int cp = (sc ^ (r & 7)) << 3;
            *(int4*)(As + (r << 6) + cp) = av[i];
            *(int4*)(Bs + (r << 6) + cp) = bv[i];
        }
        __syncthreads();

        if (k0 + 64 < D_MODEL) {
            const int h = (k0 >> 6) + 1;
#pragma unroll
            for (int i = 0; i < 4; ++i) {
                const int r  = wave * 32 + i * 8 + lr8;
                const int rg = row0 + r;
                const int b = rg >> 11, t = rg & 2047;
                av[i] = *(const int4*)(A + ((((size_t)b << 3) + h) * T_SEQ + t) * HD + (sc << 3));
                bv[i] = *(const int4*)(W + ((size_t)(col0 + r) << 9) + k0 + 64 + (sc << 3));
            }
        }

#pragma unroll
        for (int ks = 0; ks < 2; ++ks) {
            short8 af[4], bfr[4];
            const int ch = (ks << 2) + quad;
#pragma unroll
            for (int mt = 0; mt < 4; ++mt) {
                const int row = (wm << 6) + (mt << 4) + l15;
                af[mt] = *(const short8*)(As + (row << 6) + ((ch ^ (row & 7)) << 3));
            }
#pragma unroll
            for (int nt = 0; nt < 4; ++nt) {
                const int col = (wn << 6) + (nt << 4) + l15;
                bfr[nt] = *(const short8*)(Bs + (col << 6) + ((ch ^ (col & 7)) << 3));
            }
#pragma unroll
            for (int mt = 0; mt < 4; ++mt)
#pragma unroll
                for (int nt = 0; nt < 4; ++nt)
                    acc[mt][nt] = __builtin_amdgcn_mfma_f32_16x16x32_bf16(
                        af[mt], bfr[nt], acc[mt][nt], 0, 0, 0);
        }
    }

#pragma unroll
    for (int nt = 0; nt < 4; ++nt) {
        const int n = col0 + (wn << 6) + (nt << 4) + l15;
        const float bn = bias[n];
#pragma unroll
        for (int mt = 0; mt < 4; ++mt) {
#pragma unroll
            for (int reg = 0; reg < 4; ++reg) {
                const int m = row0 + (wm << 6) + (mt << 4) + (quad << 2) + reg;
                out[(size_t)m * D_MODEL + n] = acc[mt][nt][reg] + bn;
            }
        }
    }
}

// ---------------------------------------------------------------------------
extern "C" void kernel_launch(void* const* d_in, const int* in_sizes, int n_in,
                              void* d_out, int out_size, void* d_ws, size_t ws_size,
                              hipStream_t stream)
{
    const float* x        = (const float*)d_in[0];
    const int*   periods  = (const int*)  d_in[1];
    const float* in_w     = (const float*)d_in[2];
    const float* in_b     = (const float*)d_in[3];
    const float* out_w    = (const float*)d_in[4];
    const float* out_b    = (const float*)d_in[5];
    float*       out      = (float*)d_out;

    const size_t TENS = (size_t)BATCH * NHEAD * T_SEQ * HD;   // 4,194,304
    unsigned short* qb    = (unsigned short*)d_ws;
    unsigned short* kb    = qb + TENS;
    unsigned short* vb    = kb + TENS;
    unsigned short* xb    = vb + TENS;
    unsigned short* wqkvb = xb + TENS;
    unsigned short* wob   = wqkvb + (size_t)3 * D_MODEL * D_MODEL;
    unsigned short* aob   = xb;   // alias: xb dead after qkv_gemm

    // 0) all fp32 -> bf16 conversions, one launch
    cvt_all<<<(N8_X + N8_W1 + N8_W2) / 256, 256, 0, stream>>>(
        x, in_w, out_w, xb, wqkvb, wob);

    // 1) QKV projection (bf16 MFMA), XCD-swizzled flat grid
    qkv_gemm_mfma<<<(M_ROWS / 128) * ((3 * D_MODEL) / 128), 256, 0, stream>>>(
        xb, wqkvb, in_b, qb, kb, vb);

    // 2) residue-class flash attention (MFMA) -> bf16 head-major
    dim3 g2(64, BATCH * NHEAD);
    attn_rc_mfma<<<g2, 256, 0, stream>>>(qb, kb, vb, periods, aob);

    // 3) out projection (bf16 MFMA)
    dim3 g3(M_ROWS / 128, D_MODEL / 128);         // 64 x 4
    out_gemm_mfma<<<g3, 256, 0, stream>>>(aob, wob, out_b, out);
}

// Round 8
// 193.237 us; speedup vs baseline: 1.2468x; 1.2468x over previous
//
#include <hip/hip_runtime.h>
#include <math.h>

#define D_MODEL 512
#define NHEAD   8
#define HD      64
#define T_SEQ   2048
#define BATCH   4
#define M_ROWS  (BATCH * T_SEQ)   // 8192

typedef __attribute__((ext_vector_type(8))) short  short8;   // 8 bf16 = 4 VGPRs
typedef __attribute__((ext_vector_type(4))) float  floatx4;

// round-to-nearest-even fp32 -> bf16 (bit math; inputs finite)
__device__ __forceinline__ unsigned short f2bf(float f) {
    unsigned int u = __float_as_uint(f);
    unsigned int r = u + 0x7FFFu + ((u >> 16) & 1u);
    return (unsigned short)(r >> 16);
}

// pack 8 fp32 -> 8 bf16 in an int4
__device__ __forceinline__ int4 cvt8(float4 a, float4 b) {
    union { unsigned short u[8]; int4 v; } r;
    r.u[0] = f2bf(a.x); r.u[1] = f2bf(a.y); r.u[2] = f2bf(a.z); r.u[3] = f2bf(a.w);
    r.u[4] = f2bf(b.x); r.u[5] = f2bf(b.y); r.u[6] = f2bf(b.z); r.u[7] = f2bf(b.w);
    return r.v;
}

// ---------------------------------------------------------------------------
// Kernel 1: QKV projection, bf16 MFMA, fp32 inputs converted at staging
// (no separate cvt pass; L2 absorbs the cross-tile fp32 re-reads).
// Emits q/k/v bf16 head-major. XCD-swizzled flat grid. LDS epilogue for
// full-line stores.
// ---------------------------------------------------------------------------
__global__ __launch_bounds__(256) void qkv_gemm_mfma(
    const float* __restrict__ X,    // 8192 x 512 fp32
    const float* __restrict__ W,    // 1536 x 512 fp32
    const float* __restrict__ bias,
    unsigned short* __restrict__ qo, unsigned short* __restrict__ ko,
    unsigned short* __restrict__ vo)
{
    __shared__ unsigned short smem[128 * 128];    // 32 KB: As|Bs, then C-tile
    unsigned short* const As = smem;              // 128 x 64
    unsigned short* const Bs = smem + 128 * 64;   // 128 x 64

    const int bid  = blockIdx.x;
    const int xcd  = bid & 7;
    const int chk_ = bid >> 3;                            // 0..95
    const int row0 = (((chk_ / 12) << 3) + xcd) << 7;     // row-tile * 128
    const int col0 = (chk_ % 12) << 7;                    // col-tile * 128

    const int tid  = threadIdx.x;
    const int wave = tid >> 6, lane = tid & 63;
    const int quad = lane >> 4, l15 = lane & 15;
    const int wm   = wave >> 1, wn = wave & 1;
    const int lr8  = lane >> 3;       // staging: row-within-8
    const int sc   = lane & 7;        // staging: 16B chunk 0..7

    floatx4 acc[4][4] = {};

    for (int k0 = 0; k0 < D_MODEL; k0 += 64) {
        int4 av[4], bv[4];
#pragma unroll
        for (int i = 0; i < 4; ++i) {
            const int r = wave * 32 + i * 8 + lr8;
            const float* ap = X + (size_t)(row0 + r) * D_MODEL + k0 + (sc << 3);
            const float* bp = W + (size_t)(col0 + r) * D_MODEL + k0 + (sc << 3);
            av[i] = cvt8(*(const float4*)ap, *(const float4*)(ap + 4));
            bv[i] = cvt8(*(const float4*)bp, *(const float4*)(bp + 4));
        }
        __syncthreads();
#pragma unroll
        for (int i = 0; i < 4; ++i) {
            const int r  = wave * 32 + i * 8 + lr8;
            const int cp = (sc ^ (r & 7)) << 3;
            *(int4*)(As + (r << 6) + cp) = av[i];
            *(int4*)(Bs + (r << 6) + cp) = bv[i];
        }
        __syncthreads();

#pragma unroll
        for (int ks = 0; ks < 2; ++ks) {
            short8 af[4], bfr[4];
            const int ch = (ks << 2) + quad;
#pragma unroll
            for (int mt = 0; mt < 4; ++mt) {
                const int row = (wm << 6) + (mt << 4) + l15;
                af[mt] = *(const short8*)(As + (row << 6) + ((ch ^ (row & 7)) << 3));
            }
#pragma unroll
            for (int nt = 0; nt < 4; ++nt) {
                const int col = (wn << 6) + (nt << 4) + l15;
                bfr[nt] = *(const short8*)(Bs + (col << 6) + ((ch ^ (col & 7)) << 3));
            }
#pragma unroll
            for (int mt = 0; mt < 4; ++mt)
#pragma unroll
                for (int nt = 0; nt < 4; ++nt)
                    acc[mt][nt] = __builtin_amdgcn_mfma_f32_16x16x32_bf16(
                        af[mt], bfr[nt], acc[mt][nt], 0, 0, 0);
        }
    }

    // ---- epilogue: bias + bf16 -> LDS 128x128, then full-line stores ----
    __syncthreads();          // all waves done with As/Bs fragments
#pragma unroll
    for (int nt = 0; nt < 4; ++nt) {
        const int ncol = (wn << 6) + (nt << 4) + l15;
        const float bn = bias[col0 + ncol];
#pragma unroll
        for (int mt = 0; mt < 4; ++mt)
#pragma unroll
            for (int reg = 0; reg < 4; ++reg) {
                const int mrow = (wm << 6) + (mt << 4) + (quad << 2) + reg;
                smem[(mrow << 7) + ncol] = f2bf(acc[mt][nt][reg] + bn);
            }
    }
    __syncthreads();
    {
        const int c16  = lane & 15;            // 16-B chunk 0..15 (128 cols)
        const int rsub = lane >> 4;            // row-within-4
        const int n0   = col0 + (c16 << 3);
        const int part = n0 >> 9;
        unsigned short* dst = (part == 0) ? qo : ((part == 1) ? ko : vo);
        const int head = (n0 & 511) >> 6, d0 = n0 & 63;
#pragma unroll
        for (int p = 0; p < 8; ++p) {
            const int ml = (wave << 5) + (p << 2) + rsub;   // 0..127
            const int m  = row0 + ml;
            const int b = m >> 11, t = m & 2047;
            int4 val = *(const int4*)(smem + (ml << 7) + (c16 << 3));
            *(int4*)(dst + ((((size_t)b << 3) + head) * T_SEQ + t) * HD + d0) = val;
        }
    }
}

// ---------------------------------------------------------------------------
// Kernel 2: residue-class flash attention, bf16 MFMA.
// Wave-wide tile max (6 shuffles, exact) + row sums via MFMA(ones).
// ---------------------------------------------------------------------------
__global__ __launch_bounds__(256) void attn_rc_mfma(
    const unsigned short* __restrict__ q, const unsigned short* __restrict__ k,
    const unsigned short* __restrict__ v, const int* __restrict__ periods,
    unsigned short* __restrict__ o)
{
    __shared__ unsigned short Ks[64 * 64];   // [key][hd]; O-tile in epilogue
    __shared__ unsigned short Vt[64 * 64];   // [hd][key]
    __shared__ unsigned short Ps[64 * 64];   // Q tile, then P̃ [q][key]

    const int bh = blockIdx.y;
    int P = periods[bh]; if (P < 1) P = 1;
    const int q0 = T_SEQ / P, rem = T_SEQ % P;
    const int nt_hi = (q0 + 64) >> 6;
    const int nt_lo = (q0 + 63) >> 6;
    int t = blockIdx.x;
    int r, mt, Lr;
    const int hi_total = rem * nt_hi;
    if (t < hi_total) {
        r = t / nt_hi; mt = t - r * nt_hi; Lr = q0 + 1;
    } else {
        t -= hi_total;
        if (t >= (P - rem) * nt_lo) return;
        const int rr = t / nt_lo;
        r = rem + rr; mt = t - rr * nt_lo; Lr = q0;
    }
    const int m0 = mt << 6;

    const int tid  = threadIdx.x;
    const int wave = tid >> 6, lane = tid & 63;
    const int quad = lane >> 4, l15 = lane & 15;
    const int srow = tid >> 2;                 // K/Q staging row 0..63
    const int vkp  = tid & 31, vhg = tid >> 5; // V staging

    const unsigned short* hq = q + (size_t)bh * T_SEQ * HD;
    const unsigned short* hk = k + (size_t)bh * T_SEQ * HD;
    const unsigned short* hv = v + (size_t)bh * T_SEQ * HD;

    const short8 vone = {16256, 16256, 16256, 16256,
                         16256, 16256, 16256, 16256};   // bf16 1.0 x8

    // ---- stage Q tile into Ps, pull A-frags to regs ----
    {
        int m = m0 + srow; if (m > Lr - 1) m = Lr - 1;
        const unsigned short* src = hq + (size_t)(r + m * P) * HD;
#pragma unroll
        for (int rep = 0; rep < 2; ++rep) {
            const int c = ((tid & 3) << 1) + rep;
            int4 a = *(const int4*)(src + (c << 3));
            *(int4*)(Ps + (srow << 6) + ((c ^ (srow & 7)) << 3)) = a;
        }
    }
    __syncthreads();
    short8 qf[2];
#pragma unroll
    for (int ks = 0; ks < 2; ++ks) {
        const int row = (wave << 4) + l15;
        qf[ks] = *(const short8*)(Ps + (row << 6) +
                                  ((((ks << 2) + quad) ^ (row & 7)) << 3));
    }

    floatx4 Oa[4] = {};
    float m_i[4] = {-1e30f, -1e30f, -1e30f, -1e30f};
    float l_i[4] = {0.f, 0.f, 0.f, 0.f};

    for (int kt = 0; kt <= mt; ++kt) {
        const int km0 = kt << 6;

        int mk = km0 + srow; if (mk > Lr - 1) mk = Lr - 1;
        const unsigned short* ksrc = hk + (size_t)(r + mk * P) * HD;
        int4 ka[2];
#pragma unroll
        for (int rep = 0; rep < 2; ++rep)
            ka[rep] = *(const int4*)(ksrc + ((((tid & 3) << 1) + rep) << 3));
        int mv0 = km0 + (vkp << 1);     if (mv0 > Lr - 1) mv0 = Lr - 1;
        int mv1 = km0 + (vkp << 1) + 1; if (mv1 > Lr - 1) mv1 = Lr - 1;
        int4 va = *(const int4*)(hv + (size_t)(r + mv0 * P) * HD + (vhg << 3));
        int4 vb = *(const int4*)(hv + (size_t)(r + mv1 * P) * HD + (vhg << 3));

        __syncthreads();

#pragma unroll
        for (int rep = 0; rep < 2; ++rep) {
            const int c = ((tid & 3) << 1) + rep;
            *(int4*)(Ks + (srow << 6) + ((c ^ (srow & 7)) << 3)) = ka[rep];
        }
        {
            const unsigned short* pa = (const unsigned short*)&va;
            const unsigned short* pb = (const unsigned short*)&vb;
#pragma unroll
            for (int j = 0; j < 8; ++j) {
                const int hd_ = (vhg << 3) + j;
                const unsigned int pk =
                    (unsigned int)pa[j] | ((unsigned int)pb[j] << 16);
                *(unsigned int*)((char*)Vt + (hd_ << 7) +
                                 ((((vkp >> 2) ^ (hd_ & 7)) << 4)) +
                                 ((vkp & 3) << 2)) = pk;
            }
        }
        __syncthreads();

        // ---- QK^T ----
        floatx4 sacc[4] = {};
#pragma unroll
        for (int nt = 0; nt < 4; ++nt) {
            const int row = (nt << 4) + l15;
#pragma unroll
            for (int ks = 0; ks < 2; ++ks) {
                short8 kf = *(const short8*)(Ks + (row << 6) +
                                             ((((ks << 2) + quad) ^ (row & 7)) << 3));
                sacc[nt] = __builtin_amdgcn_mfma_f32_16x16x32_bf16(
                    qf[ks], kf, sacc[nt], 0, 0, 0);
            }
        }

        // ---- scale + causal mask; wave-wide tile max ----
        const bool diag = (kt == mt);
        float s[4][4];                        // [nt][reg]
        float tm = -1e30f;
#pragma unroll
        for (int nt = 0; nt < 4; ++nt)
#pragma unroll
            for (int reg = 0; reg < 4; ++reg) {
                float sv = sacc[nt][reg] * 0.125f;
                if (diag) {
                    const int sq = (wave << 4) + (quad << 2) + reg;
                    if (((nt << 4) + l15) > sq) sv = -1e30f;
                }
                s[nt][reg] = sv;
                tm = fmaxf(tm, sv);
            }
        tm = fmaxf(tm, __shfl_xor(tm, 1));
        tm = fmaxf(tm, __shfl_xor(tm, 2));
        tm = fmaxf(tm, __shfl_xor(tm, 4));
        tm = fmaxf(tm, __shfl_xor(tm, 8));
        tm = fmaxf(tm, __shfl_xor(tm, 16));
        tm = fmaxf(tm, __shfl_xor(tm, 32));

        float sc[4];
#pragma unroll
        for (int reg = 0; reg < 4; ++reg) {
            const float nm = fmaxf(m_i[reg], tm);
            sc[reg] = __expf(m_i[reg] - nm);
            m_i[reg] = nm;
        }

        // ---- P̃ -> Ps [q][key] bf16 (own-wave rows only) ----
#pragma unroll
        for (int reg = 0; reg < 4; ++reg) {
            const int row = (wave << 4) + (quad << 2) + reg;
#pragma unroll
            for (int nt = 0; nt < 4; ++nt) {
                const int col = (nt << 4) + l15;
                *((unsigned short*)((char*)Ps + (row << 7) +
                                    (((col >> 3) ^ (row & 7)) << 4) +
                                    ((col & 7) << 1))) =
                    f2bf(__expf(s[nt][reg] - m_i[reg]));
            }
        }

        // ---- read P̃ A-frags; row sums via MFMA(ones); l update ----
        short8 pf[2];
#pragma unroll
        for (int ks = 0; ks < 2; ++ks) {
            const int row = (wave << 4) + l15;
            pf[ks] = *(const short8*)(Ps + (row << 6) +
                                      ((((ks << 2) + quad) ^ (row & 7)) << 3));
        }
        floatx4 ls = {};
        ls = __builtin_amdgcn_mfma_f32_16x16x32_bf16(pf[0], vone, ls, 0, 0, 0);
        ls = __builtin_amdgcn_mfma_f32_16x16x32_bf16(pf[1], vone, ls, 0, 0, 0);
#pragma unroll
        for (int reg = 0; reg < 4; ++reg)
            l_i[reg] = l_i[reg] * sc[reg] + ls[reg];

        // ---- PV ----
#pragma unroll
        for (int nt = 0; nt < 4; ++nt)
#pragma unroll
            for (int reg = 0; reg < 4; ++reg)
                Oa[nt][reg] *= sc[reg];
#pragma unroll
        for (int nt = 0; nt < 4; ++nt) {
            const int row = (nt << 4) + l15;
#pragma unroll
            for (int ks = 0; ks < 2; ++ks) {
                short8 vf = *(const short8*)(Vt + (row << 6) +
                                             ((((ks << 2) + quad) ^ (row & 7)) << 3));
                Oa[nt] = __builtin_amdgcn_mfma_f32_16x16x32_bf16(
                    pf[ks], vf, Oa[nt], 0, 0, 0);
            }
        }
    }

    // ---- epilogue: O through LDS (Ks dead), full-line stores ----
    __syncthreads();          // all waves done reading Ks/Vt
#pragma unroll
    for (int reg = 0; reg < 4; ++reg) {
        const float invl = 1.f / l_i[reg];
        const int row = (wave << 4) + (quad << 2) + reg;
#pragma unroll
        for (int nt = 0; nt < 4; ++nt)
            Ks[(row << 6) + (nt << 4) + l15] = f2bf(Oa[nt][reg] * invl);
    }
    {
        const int lrow = lane >> 2;
        const int chk  = (lane & 3) << 1;
        const int ml   = (wave << 4) + lrow;
        const int m    = m0 + ml;
        if (m < Lr) {
            const size_t base = ((size_t)bh * T_SEQ + (r + m * P)) * HD;
            int4 w0 = *(const int4*)(Ks + (ml << 6) + (chk << 3));
            int4 w1 = *(const int4*)(Ks + (ml << 6) + ((chk + 1) << 3));
            *(int4*)(o + base + (chk << 3))       = w0;
            *(int4*)(o + base + ((chk + 1) << 3)) = w1;
        }
    }
}

// ---------------------------------------------------------------------------
// Kernel 3: out projection, bf16 MFMA; A head-major bf16, W fp32 converted
// at staging (L2-resident, 1 MB).
// ---------------------------------------------------------------------------
__global__ __launch_bounds__(256) void out_gemm_mfma(
    const unsigned short* __restrict__ A,
    const float* __restrict__ W,            // 512 x 512 fp32
    const float* __restrict__ bias,
    float* __restrict__ out)
{
    __shared__ unsigned short As[128 * 64];
    __shared__ unsigned short Bs[128 * 64];

    const int tid  = threadIdx.x;
    const int wave = tid >> 6, lane = tid & 63;
    const int quad = lane >> 4, l15 = lane & 15;
    const int wm   = wave >> 1, wn = wave & 1;
    const int row0 = blockIdx.x * 128;
    const int col0 = blockIdx.y * 128;
    const int lr8  = lane >> 3;
    const int sc   = lane & 7;

    floatx4 acc[4][4] = {};

    for (int k0 = 0; k0 < D_MODEL; k0 += 64) {
        const int h = k0 >> 6;
        int4 av[4], bv[4];
#pragma unroll
        for (int i = 0; i < 4; ++i) {
            const int r  = wave * 32 + i * 8 + lr8;
            const int rg = row0 + r;
            const int b = rg >> 11, t = rg & 2047;
            av[i] = *(const int4*)(A + ((((size_t)b << 3) + h) * T_SEQ + t) * HD + (sc << 3));
            const float* bp = W + (size_t)(col0 + r) * D_MODEL + k0 + (sc << 3);
            bv[i] = cvt8(*(const float4*)bp, *(const float4*)(bp + 4));
        }
        __syncthreads();
#pragma unroll
        for (int i = 0; i < 4; ++i) {
            const int r  = wave * 32 + i * 8 + lr8;
            const int cp = (sc ^ (r & 7)) << 3;
            *(int4*)(As + (r << 6) + cp) = av[i];
            *(int4*)(Bs + (r << 6) + cp) = bv[i];
        }
        __syncthreads();

#pragma unroll
        for (int ks = 0; ks < 2; ++ks) {
            short8 af[4], bfr[4];
            const int ch = (ks << 2) + quad;
#pragma unroll
            for (int mt = 0; mt < 4; ++mt) {
                const int row = (wm << 6) + (mt << 4) + l15;
                af[mt] = *(const short8*)(As + (row << 6) + ((ch ^ (row & 7)) << 3));
            }
#pragma unroll
            for (int nt = 0; nt < 4; ++nt) {
                const int col = (wn << 6) + (nt << 4) + l15;
                bfr[nt] = *(const short8*)(Bs + (col << 6) + ((ch ^ (col & 7)) << 3));
            }
#pragma unroll
            for (int mt = 0; mt < 4; ++mt)
#pragma unroll
                for (int nt = 0; nt < 4; ++nt)
                    acc[mt][nt] = __builtin_amdgcn_mfma_f32_16x16x32_bf16(
                        af[mt], bfr[nt], acc[mt][nt], 0, 0, 0);
        }
    }

#pragma unroll
    for (int nt = 0; nt < 4; ++nt) {
        const int n = col0 + (wn << 6) + (nt << 4) + l15;
        const float bn = bias[n];
#pragma unroll
        for (int mt = 0; mt < 4; ++mt) {
#pragma unroll
            for (int reg = 0; reg < 4; ++reg) {
                const int m = row0 + (wm << 6) + (mt << 4) + (quad << 2) + reg;
                out[(size_t)m * D_MODEL + n] = acc[mt][nt][reg] + bn;
            }
        }
    }
}

// ---------------------------------------------------------------------------
extern "C" void kernel_launch(void* const* d_in, const int* in_sizes, int n_in,
                              void* d_out, int out_size, void* d_ws, size_t ws_size,
                              hipStream_t stream)
{
    const float* x        = (const float*)d_in[0];
    const int*   periods  = (const int*)  d_in[1];
    const float* in_w     = (const float*)d_in[2];
    const float* in_b     = (const float*)d_in[3];
    const float* out_w    = (const float*)d_in[4];
    const float* out_b    = (const float*)d_in[5];
    float*       out      = (float*)d_out;

    const size_t TENS = (size_t)BATCH * NHEAD * T_SEQ * HD;   // 4,194,304
    unsigned short* qb  = (unsigned short*)d_ws;
    unsigned short* kb  = qb + TENS;
    unsigned short* vb  = kb + TENS;
    unsigned short* aob = vb + TENS;
    // ws usage: 4 * 8 MB = 32 MB

    // 1) QKV projection (bf16 MFMA, fp32 inputs), XCD-swizzled flat grid
    qkv_gemm_mfma<<<(M_ROWS / 128) * ((3 * D_MODEL) / 128), 256, 0, stream>>>(
        x, in_w, in_b, qb, kb, vb);

    // 2) residue-class flash attention (MFMA) -> bf16 head-major
    dim3 g2(64, BATCH * NHEAD);
    attn_rc_mfma<<<g2, 256, 0, stream>>>(qb, kb, vb, periods, aob);

    // 3) out projection (bf16 MFMA, fp32 weights)
    dim3 g3(M_ROWS / 128, D_MODEL / 128);         // 64 x 4
    out_gemm_mfma<<<g3, 256, 0, stream>>>(aob, out_w, out_b, out);
}

// Round 9
// 172.614 us; speedup vs baseline: 1.3958x; 1.1195x over previous
//
#include <hip/hip_runtime.h>
#include <math.h>

#define D_MODEL 512
#define NHEAD   8
#define HD      64
#define T_SEQ   2048
#define BATCH   4
#define M_ROWS  (BATCH * T_SEQ)   // 8192

typedef __attribute__((ext_vector_type(8))) short  short8;   // 8 bf16 = 4 VGPRs
typedef __attribute__((ext_vector_type(4))) float  floatx4;

// round-to-nearest-even fp32 -> bf16 (bit math; inputs finite)
__device__ __forceinline__ unsigned short f2bf(float f) {
    unsigned int u = __float_as_uint(f);
    unsigned int r = u + 0x7FFFu + ((u >> 16) & 1u);
    return (unsigned short)(r >> 16);
}

__device__ __forceinline__ float bf2f(unsigned short u) {
    return __uint_as_float((unsigned int)u << 16);
}

// pack 8 fp32 -> 8 bf16 in an int4
__device__ __forceinline__ int4 cvt8(float4 a, float4 b) {
    union { unsigned short u[8]; int4 v; } r;
    r.u[0] = f2bf(a.x); r.u[1] = f2bf(a.y); r.u[2] = f2bf(a.z); r.u[3] = f2bf(a.w);
    r.u[4] = f2bf(b.x); r.u[5] = f2bf(b.y); r.u[6] = f2bf(b.z); r.u[7] = f2bf(b.w);
    return r.v;
}

// ---------------------------------------------------------------------------
// Kernel 1: QKV projection, bf16 MFMA, fp32 inputs converted at staging.
// ---------------------------------------------------------------------------
__global__ __launch_bounds__(256) void qkv_gemm_mfma(
    const float* __restrict__ X,    // 8192 x 512 fp32
    const float* __restrict__ W,    // 1536 x 512 fp32
    const float* __restrict__ bias,
    unsigned short* __restrict__ qo, unsigned short* __restrict__ ko,
    unsigned short* __restrict__ vo)
{
    __shared__ unsigned short smem[128 * 128];    // 32 KB: As|Bs, then C-tile
    unsigned short* const As = smem;              // 128 x 64
    unsigned short* const Bs = smem + 128 * 64;   // 128 x 64

    const int bid  = blockIdx.x;
    const int xcd  = bid & 7;
    const int chk_ = bid >> 3;                            // 0..95
    const int row0 = (((chk_ / 12) << 3) + xcd) << 7;     // row-tile * 128
    const int col0 = (chk_ % 12) << 7;                    // col-tile * 128

    const int tid  = threadIdx.x;
    const int wave = tid >> 6, lane = tid & 63;
    const int quad = lane >> 4, l15 = lane & 15;
    const int wm   = wave >> 1, wn = wave & 1;
    const int lr8  = lane >> 3;       // staging: row-within-8
    const int sc   = lane & 7;        // staging: 16B chunk 0..7

    floatx4 acc[4][4] = {};

    for (int k0 = 0; k0 < D_MODEL; k0 += 64) {
        int4 av[4], bv[4];
#pragma unroll
        for (int i = 0; i < 4; ++i) {
            const int r = wave * 32 + i * 8 + lr8;
            const float* ap = X + (size_t)(row0 + r) * D_MODEL + k0 + (sc << 3);
            const float* bp = W + (size_t)(col0 + r) * D_MODEL + k0 + (sc << 3);
            av[i] = cvt8(*(const float4*)ap, *(const float4*)(ap + 4));
            bv[i] = cvt8(*(const float4*)bp, *(const float4*)(bp + 4));
        }
        __syncthreads();
#pragma unroll
        for (int i = 0; i < 4; ++i) {
            const int r  = wave * 32 + i * 8 + lr8;
            const int cp = (sc ^ (r & 7)) << 3;
            *(int4*)(As + (r << 6) + cp) = av[i];
            *(int4*)(Bs + (r << 6) + cp) = bv[i];
        }
        __syncthreads();

#pragma unroll
        for (int ks = 0; ks < 2; ++ks) {
            short8 af[4], bfr[4];
            const int ch = (ks << 2) + quad;
#pragma unroll
            for (int mt = 0; mt < 4; ++mt) {
                const int row = (wm << 6) + (mt << 4) + l15;
                af[mt] = *(const short8*)(As + (row << 6) + ((ch ^ (row & 7)) << 3));
            }
#pragma unroll
            for (int nt = 0; nt < 4; ++nt) {
                const int col = (wn << 6) + (nt << 4) + l15;
                bfr[nt] = *(const short8*)(Bs + (col << 6) + ((ch ^ (col & 7)) << 3));
            }
#pragma unroll
            for (int mt = 0; mt < 4; ++mt)
#pragma unroll
                for (int nt = 0; nt < 4; ++nt)
                    acc[mt][nt] = __builtin_amdgcn_mfma_f32_16x16x32_bf16(
                        af[mt], bfr[nt], acc[mt][nt], 0, 0, 0);
        }
    }

    // ---- epilogue: bias + bf16 -> LDS 128x128, then full-line stores ----
    __syncthreads();
#pragma unroll
    for (int nt = 0; nt < 4; ++nt) {
        const int ncol = (wn << 6) + (nt << 4) + l15;
        const float bn = bias[col0 + ncol];
#pragma unroll
        for (int mt = 0; mt < 4; ++mt)
#pragma unroll
            for (int reg = 0; reg < 4; ++reg) {
                const int mrow = (wm << 6) + (mt << 4) + (quad << 2) + reg;
                smem[(mrow << 7) + ncol] = f2bf(acc[mt][nt][reg] + bn);
            }
    }
    __syncthreads();
    {
        const int c16  = lane & 15;
        const int rsub = lane >> 4;
        const int n0   = col0 + (c16 << 3);
        const int part = n0 >> 9;
        unsigned short* dst = (part == 0) ? qo : ((part == 1) ? ko : vo);
        const int head = (n0 & 511) >> 6, d0 = n0 & 63;
#pragma unroll
        for (int p = 0; p < 8; ++p) {
            const int ml = (wave << 5) + (p << 2) + rsub;
            const int m  = row0 + ml;
            const int b = m >> 11, t = m & 2047;
            int4 val = *(const int4*)(smem + (ml << 7) + (c16 << 3));
            *(int4*)(dst + ((((size_t)b << 3) + head) * T_SEQ + t) * HD + d0) = val;
        }
    }
}

// ---------------------------------------------------------------------------
// Kernel 2: residue-class flash attention, bf16 MFMA, split-K + dbuf.
// blockIdx.z = chunk c (16 k-tiles each).  mt>=16 occurs only for P==1; those
// slots write unnormalized partials (O, m, l) merged by reduce_p1.  All other
// slots are single-chunk and write the final output directly.
// K/V staging is double-buffered with ONE barrier per k-tile iteration;
// next tile's global loads issue at iteration top and stage after compute.
// ---------------------------------------------------------------------------
__global__ __launch_bounds__(256) void attn_rc_mfma(
    const unsigned short* __restrict__ q, const unsigned short* __restrict__ k,
    const unsigned short* __restrict__ v, const int* __restrict__ periods,
    unsigned short* __restrict__ o,
    unsigned short* __restrict__ Opart, float* __restrict__ Mpart,
    float* __restrict__ Lpart)
{
    __shared__ unsigned short Ks[2][64 * 64];   // [key][hd]; [0] = epilogue scratch
    __shared__ unsigned short Vt[2][64 * 64];   // [hd][key]
    __shared__ unsigned short Ps[64 * 64];      // Q tile, then P̃ [q][key]

    const int bh = blockIdx.y;
    int P = periods[bh]; if (P < 1) P = 1;
    const int q0 = T_SEQ / P, rem = T_SEQ % P;
    const int nt_hi = (q0 + 64) >> 6;
    const int nt_lo = (q0 + 63) >> 6;
    int t = blockIdx.x;
    const int c = blockIdx.z;
    int r, mt, Lr;
    const int hi_total = rem * nt_hi;
    if (t < hi_total) {
        r = t / nt_hi; mt = t - r * nt_hi; Lr = q0 + 1;
    } else {
        t -= hi_total;
        if (t >= (P - rem) * nt_lo) return;
        const int rr = t / nt_lo;
        r = rem + rr; mt = t - rr * nt_lo; Lr = q0;
    }
    if (c == 1 && mt < 16) return;
    const int kt0  = c << 4;
    const int kend = (c == 0) ? (mt < 15 ? mt : 15) : mt;
    const int m0 = mt << 6;

    const int tid  = threadIdx.x;
    const int wave = tid >> 6, lane = tid & 63;
    const int quad = lane >> 4, l15 = lane & 15;
    const int srow = tid >> 2;                 // K/Q staging row 0..63
    const int vkp  = tid & 31, vhg = tid >> 5; // V staging

    const unsigned short* hq = q + (size_t)bh * T_SEQ * HD;
    const unsigned short* hk = k + (size_t)bh * T_SEQ * HD;
    const unsigned short* hv = v + (size_t)bh * T_SEQ * HD;

    const short8 vone = {16256, 16256, 16256, 16256,
                         16256, 16256, 16256, 16256};   // bf16 1.0 x8

    // ---- stage Q tile into Ps + first K/V tile into buf 0, one barrier ----
    {
        int m = m0 + srow; if (m > Lr - 1) m = Lr - 1;
        const unsigned short* src = hq + (size_t)(r + m * P) * HD;
#pragma unroll
        for (int rep = 0; rep < 2; ++rep) {
            const int cc = ((tid & 3) << 1) + rep;
            int4 a = *(const int4*)(src + (cc << 3));
            *(int4*)(Ps + (srow << 6) + ((cc ^ (srow & 7)) << 3)) = a;
        }
    }
    {
        const int km0 = kt0 << 6;
        int mk = km0 + srow; if (mk > Lr - 1) mk = Lr - 1;
        const unsigned short* ksrc = hk + (size_t)(r + mk * P) * HD;
#pragma unroll
        for (int rep = 0; rep < 2; ++rep) {
            const int cc = ((tid & 3) << 1) + rep;
            int4 a = *(const int4*)(ksrc + (cc << 3));
            *(int4*)(Ks[0] + (srow << 6) + ((cc ^ (srow & 7)) << 3)) = a;
        }
        int mv0 = km0 + (vkp << 1);     if (mv0 > Lr - 1) mv0 = Lr - 1;
        int mv1 = km0 + (vkp << 1) + 1; if (mv1 > Lr - 1) mv1 = Lr - 1;
        int4 va = *(const int4*)(hv + (size_t)(r + mv0 * P) * HD + (vhg << 3));
        int4 vb = *(const int4*)(hv + (size_t)(r + mv1 * P) * HD + (vhg << 3));
        const unsigned short* pa = (const unsigned short*)&va;
        const unsigned short* pb = (const unsigned short*)&vb;
#pragma unroll
        for (int j = 0; j < 8; ++j) {
            const int hd_ = (vhg << 3) + j;
            const unsigned int pk =
                (unsigned int)pa[j] | ((unsigned int)pb[j] << 16);
            *(unsigned int*)((char*)Vt[0] + (hd_ << 7) +
                             ((((vkp >> 2) ^ (hd_ & 7)) << 4)) +
                             ((vkp & 3) << 2)) = pk;
        }
    }
    __syncthreads();
    short8 qf[2];
#pragma unroll
    for (int ks = 0; ks < 2; ++ks) {
        const int row = (wave << 4) + l15;
        qf[ks] = *(const short8*)(Ps + (row << 6) +
                                  ((((ks << 2) + quad) ^ (row & 7)) << 3));
    }

    floatx4 Oa[4] = {};
    float m_i[4] = {-1e30f, -1e30f, -1e30f, -1e30f};
    float l_i[4] = {0.f, 0.f, 0.f, 0.f};

    for (int kt = kt0; kt <= kend; ++kt) {
        const int buf = (kt - kt0) & 1;
        const bool havenext = kt < kend;

        // ---- prefetch next tile's globals (overlaps compute below) ----
        int4 ka[2], va, vb;
        if (havenext) {
            const int km0 = (kt + 1) << 6;
            int mk = km0 + srow; if (mk > Lr - 1) mk = Lr - 1;
            const unsigned short* ksrc = hk + (size_t)(r + mk * P) * HD;
#pragma unroll
            for (int rep = 0; rep < 2; ++rep)
                ka[rep] = *(const int4*)(ksrc + ((((tid & 3) << 1) + rep) << 3));
            int mv0 = km0 + (vkp << 1);     if (mv0 > Lr - 1) mv0 = Lr - 1;
            int mv1 = km0 + (vkp << 1) + 1; if (mv1 > Lr - 1) mv1 = Lr - 1;
            va = *(const int4*)(hv + (size_t)(r + mv0 * P) * HD + (vhg << 3));
            vb = *(const int4*)(hv + (size_t)(r + mv1 * P) * HD + (vhg << 3));
        }

        // ---- QK^T from Ks[buf] ----
        floatx4 sacc[4] = {};
#pragma unroll
        for (int nt = 0; nt < 4; ++nt) {
            const int row = (nt << 4) + l15;
#pragma unroll
            for (int ks = 0; ks < 2; ++ks) {
                short8 kf = *(const short8*)(Ks[buf] + (row << 6) +
                                             ((((ks << 2) + quad) ^ (row & 7)) << 3));
                sacc[nt] = __builtin_amdgcn_mfma_f32_16x16x32_bf16(
                    qf[ks], kf, sacc[nt], 0, 0, 0);
            }
        }

        // ---- scale + causal mask; wave-wide tile max ----
        const bool diag = (kt == mt);
        float s[4][4];
        float tm = -1e30f;
#pragma unroll
        for (int nt = 0; nt < 4; ++nt)
#pragma unroll
            for (int reg = 0; reg < 4; ++reg) {
                float sv = sacc[nt][reg] * 0.125f;
                if (diag) {
                    const int sq = (wave << 4) + (quad << 2) + reg;
                    if (((nt << 4) + l15) > sq) sv = -1e30f;
                }
                s[nt][reg] = sv;
                tm = fmaxf(tm, sv);
            }
        tm = fmaxf(tm, __shfl_xor(tm, 1));
        tm = fmaxf(tm, __shfl_xor(tm, 2));
        tm = fmaxf(tm, __shfl_xor(tm, 4));
        tm = fmaxf(tm, __shfl_xor(tm, 8));
        tm = fmaxf(tm, __shfl_xor(tm, 16));
        tm = fmaxf(tm, __shfl_xor(tm, 32));

        float sc[4];
#pragma unroll
        for (int reg = 0; reg < 4; ++reg) {
            const float nm = fmaxf(m_i[reg], tm);
            sc[reg] = __expf(m_i[reg] - nm);
            m_i[reg] = nm;
        }

        // ---- P̃ -> Ps (own-wave rows) ----
#pragma unroll
        for (int reg = 0; reg < 4; ++reg) {
            const int row = (wave << 4) + (quad << 2) + reg;
#pragma unroll
            for (int nt = 0; nt < 4; ++nt) {
                const int col = (nt << 4) + l15;
                *((unsigned short*)((char*)Ps + (row << 7) +
                                    (((col >> 3) ^ (row & 7)) << 4) +
                                    ((col & 7) << 1))) =
                    f2bf(__expf(s[nt][reg] - m_i[reg]));
            }
        }

        // ---- pf reads; row sums via MFMA(ones); l update ----
        short8 pf[2];
#pragma unroll
        for (int ks = 0; ks < 2; ++ks) {
            const int row = (wave << 4) + l15;
            pf[ks] = *(const short8*)(Ps + (row << 6) +
                                      ((((ks << 2) + quad) ^ (row & 7)) << 3));
        }
        floatx4 ls = {};
        ls = __builtin_amdgcn_mfma_f32_16x16x32_bf16(pf[0], vone, ls, 0, 0, 0);
        ls = __builtin_amdgcn_mfma_f32_16x16x32_bf16(pf[1], vone, ls, 0, 0, 0);
#pragma unroll
        for (int reg = 0; reg < 4; ++reg)
            l_i[reg] = l_i[reg] * sc[reg] + ls[reg];

        // ---- PV from Vt[buf] ----
#pragma unroll
        for (int nt = 0; nt < 4; ++nt)
#pragma unroll
            for (int reg = 0; reg < 4; ++reg)
                Oa[nt][reg] *= sc[reg];
#pragma unroll
        for (int nt = 0; nt < 4; ++nt) {
            const int row = (nt << 4) + l15;
#pragma unroll
            for (int ks = 0; ks < 2; ++ks) {
                short8 vf = *(const short8*)(Vt[buf] + (row << 6) +
                                             ((((ks << 2) + quad) ^ (row & 7)) << 3));
                Oa[nt] = __builtin_amdgcn_mfma_f32_16x16x32_bf16(
                    pf[ks], vf, Oa[nt], 0, 0, 0);
            }
        }

        // ---- stage next tile into the other buffer; ONE barrier ----
        if (havenext) {
#pragma unroll
            for (int rep = 0; rep < 2; ++rep) {
                const int cc = ((tid & 3) << 1) + rep;
                *(int4*)(Ks[buf ^ 1] + (srow << 6) + ((cc ^ (srow & 7)) << 3)) = ka[rep];
            }
            const unsigned short* pa = (const unsigned short*)&va;
            const unsigned short* pb = (const unsigned short*)&vb;
#pragma unroll
            for (int j = 0; j < 8; ++j) {
                const int hd_ = (vhg << 3) + j;
                const unsigned int pk =
                    (unsigned int)pa[j] | ((unsigned int)pb[j] << 16);
                *(unsigned int*)((char*)Vt[buf ^ 1] + (hd_ << 7) +
                                 ((((vkp >> 2) ^ (hd_ & 7)) << 4)) +
                                 ((vkp & 3) << 2)) = pk;
            }
        }
        __syncthreads();
    }

    const bool single = (kt0 == 0) && (kend == mt);
    if (single) {
        // ---- direct epilogue: normalize + scatter via LDS (Ks[0] scratch) ----
#pragma unroll
        for (int reg = 0; reg < 4; ++reg) {
            const float invl = 1.f / l_i[reg];
            const int row = (wave << 4) + (quad << 2) + reg;
#pragma unroll
            for (int nt = 0; nt < 4; ++nt)
                Ks[0][(row << 6) + (nt << 4) + l15] = f2bf(Oa[nt][reg] * invl);
        }
        const int lrow = lane >> 2;
        const int chk  = (lane & 3) << 1;
        const int ml   = (wave << 4) + lrow;
        const int m    = m0 + ml;
        if (m < Lr) {
            const size_t base = ((size_t)bh * T_SEQ + (r + m * P)) * HD;
            int4 w0 = *(const int4*)(Ks[0] + (ml << 6) + (chk << 3));
            int4 w1 = *(const int4*)(Ks[0] + (ml << 6) + ((chk + 1) << 3));
            *(int4*)(o + base + (chk << 3))       = w0;
            *(int4*)(o + base + ((chk + 1) << 3)) = w1;
        }
    } else {
        // ---- partial epilogue: unnormalized O + (m,l) for reduce_p1 ----
        const int slot = (((bh << 5) + mt) << 1) + c;   // mt>=16 only for P==1
#pragma unroll
        for (int reg = 0; reg < 4; ++reg) {
            const int row = (wave << 4) + (quad << 2) + reg;
#pragma unroll
            for (int nt = 0; nt < 4; ++nt)
                Ks[0][(row << 6) + (nt << 4) + l15] = f2bf(Oa[nt][reg]);
            if (l15 == 0) {
                Mpart[(size_t)slot * 64 + row] = m_i[reg];
                Lpart[(size_t)slot * 64 + row] = l_i[reg];
            }
        }
        const int lrow = lane >> 2;
        const int chk  = (lane & 3) << 1;
        const int ml   = (wave << 4) + lrow;
        unsigned short* dst = Opart + (size_t)slot * 4096 + (ml << 6);
        *(int4*)(dst + (chk << 3))       = *(const int4*)(Ks[0] + (ml << 6) + (chk << 3));
        *(int4*)(dst + ((chk + 1) << 3)) = *(const int4*)(Ks[0] + (ml << 6) + ((chk + 1) << 3));
    }
}

// ---------------------------------------------------------------------------
// Kernel 2b: merge the two chunks of P==1 slots (t = 16..31).
// ---------------------------------------------------------------------------
__global__ __launch_bounds__(256) void reduce_p1(
    const int* __restrict__ periods,
    const unsigned short* __restrict__ Opart, const float* __restrict__ Mpart,
    const float* __restrict__ Lpart, unsigned short* __restrict__ o)
{
    const int bh = blockIdx.y;
    int P = periods[bh]; if (P < 1) P = 1;
    if (P != 1) return;
    const int t = blockIdx.x + 16;              // mt = t, two chunks exist

    const int tid = threadIdx.x;
    const int row = tid >> 2;
    const int cg  = (tid & 3) << 4;             // 16 cols per thread

    const size_t slot0 = ((((size_t)bh << 5) + t) << 1);
    const float m0 = Mpart[slot0 * 64 + row], m1 = Mpart[(slot0 + 1) * 64 + row];
    const float l0 = Lpart[slot0 * 64 + row], l1 = Lpart[(slot0 + 1) * 64 + row];
    const float mm = fmaxf(m0, m1);
    const float a0 = __expf(m0 - mm), a1 = __expf(m1 - mm);
    const float inv = 1.f / (a0 * l0 + a1 * l1);

    const unsigned short* p0 = Opart + slot0 * 4096 + (row << 6) + cg;
    const unsigned short* p1 = p0 + 4096;
    unsigned short outv[16];
#pragma unroll
    for (int j = 0; j < 16; ++j)
        outv[j] = f2bf((a0 * bf2f(p0[j]) + a1 * bf2f(p1[j])) * inv);

    unsigned short* dst = o + (((size_t)bh * T_SEQ) + (t << 6) + row) * HD + cg;
    *(int4*)dst       = *(const int4*)&outv[0];
    *(int4*)(dst + 8) = *(const int4*)&outv[8];
}

// ---------------------------------------------------------------------------
// Kernel 3: out projection, bf16 MFMA; A head-major bf16, W fp32 converted
// at staging.
// ---------------------------------------------------------------------------
__global__ __launch_bounds__(256) void out_gemm_mfma(
    const unsigned short* __restrict__ A,
    const float* __restrict__ W,            // 512 x 512 fp32
    const float* __restrict__ bias,
    float* __restrict__ out)
{
    __shared__ unsigned short As[128 * 64];
    __shared__ unsigned short Bs[128 * 64];

    const int tid  = threadIdx.x;
    const int wave = tid >> 6, lane = tid & 63;
    const int quad = lane >> 4, l15 = lane & 15;
    const int wm   = wave >> 1, wn = wave & 1;
    const int row0 = blockIdx.x * 128;
    const int col0 = blockIdx.y * 128;
    const int lr8  = lane >> 3;
    const int sc   = lane & 7;

    floatx4 acc[4][4] = {};

    for (int k0 = 0; k0 < D_MODEL; k0 += 64) {
        const int h = k0 >> 6;
        int4 av[4], bv[4];
#pragma unroll
        for (int i = 0; i < 4; ++i) {
            const int r  = wave * 32 + i * 8 + lr8;
            const int rg = row0 + r;
            const int b = rg >> 11, t = rg & 2047;
            av[i] = *(const int4*)(A + ((((size_t)b << 3) + h) * T_SEQ + t) * HD + (sc << 3));
            const float* bp = W + (size_t)(col0 + r) * D_MODEL + k0 + (sc << 3);
            bv[i] = cvt8(*(const float4*)bp, *(const float4*)(bp + 4));
        }
        __syncthreads();
#pragma unroll
        for (int i = 0; i < 4; ++i) {
            const int r  = wave * 32 + i * 8 + lr8;
            const int cp = (sc ^ (r & 7)) << 3;
            *(int4*)(As + (r << 6) + cp) = av[i];
            *(int4*)(Bs + (r << 6) + cp) = bv[i];
        }
        __syncthreads();

#pragma unroll
        for (int ks = 0; ks < 2; ++ks) {
            short8 af[4], bfr[4];
            const int ch = (ks << 2) + quad;
#pragma unroll
            for (int mt = 0; mt < 4; ++mt) {
                const int row = (wm << 6) + (mt << 4) + l15;
                af[mt] = *(const short8*)(As + (row << 6) + ((ch ^ (row & 7)) << 3));
            }
#pragma unroll
            for (int nt = 0; nt < 4; ++nt) {
                const int col = (wn << 6) + (nt << 4) + l15;
                bfr[nt] = *(const short8*)(Bs + (col << 6) + ((ch ^ (col & 7)) << 3));
            }
#pragma unroll
            for (int mt = 0; mt < 4; ++mt)
#pragma unroll
                for (int nt = 0; nt < 4; ++nt)
                    acc[mt][nt] = __builtin_amdgcn_mfma_f32_16x16x32_bf16(
                        af[mt], bfr[nt], acc[mt][nt], 0, 0, 0);
        }
    }

#pragma unroll
    for (int nt = 0; nt < 4; ++nt) {
        const int n = col0 + (wn << 6) + (nt << 4) + l15;
        const float bn = bias[n];
#pragma unroll
        for (int mt = 0; mt < 4; ++mt) {
#pragma unroll
            for (int reg = 0; reg < 4; ++reg) {
                const int m = row0 + (wm << 6) + (mt << 4) + (quad << 2) + reg;
                out[(size_t)m * D_MODEL + n] = acc[mt][nt][reg] + bn;
            }
        }
    }
}

// ---------------------------------------------------------------------------
extern "C" void kernel_launch(void* const* d_in, const int* in_sizes, int n_in,
                              void* d_out, int out_size, void* d_ws, size_t ws_size,
                              hipStream_t stream)
{
    const float* x        = (const float*)d_in[0];
    const int*   periods  = (const int*)  d_in[1];
    const float* in_w     = (const float*)d_in[2];
    const float* in_b     = (const float*)d_in[3];
    const float* out_w    = (const float*)d_in[4];
    const float* out_b    = (const float*)d_in[5];
    float*       out      = (float*)d_out;

    const size_t TENS = (size_t)BATCH * NHEAD * T_SEQ * HD;   // 4,194,304
    unsigned short* qb    = (unsigned short*)d_ws;
    unsigned short* kb    = qb + TENS;
    unsigned short* vb    = kb + TENS;
    unsigned short* aob   = vb + TENS;
    unsigned short* Opart = aob + TENS;                       // 2048 slots x 4096
    float*          Mpart = (float*)(Opart + (size_t)2048 * 4096);
    float*          Lpart = Mpart + (size_t)2048 * 64;
    // ws usage: 4*8.4MB + 16.8MB + 0.5MB + 0.5MB ~= 51.4 MB

    // 1) QKV projection (bf16 MFMA, fp32 inputs), XCD-swizzled flat grid
    qkv_gemm_mfma<<<(M_ROWS / 128) * ((3 * D_MODEL) / 128), 256, 0, stream>>>(
        x, in_w, in_b, qb, kb, vb);

    // 2) residue-class flash attention, split-K chunks of 16 k-tiles
    dim3 g2(64, BATCH * NHEAD, 2);
    attn_rc_mfma<<<g2, 256, 0, stream>>>(qb, kb, vb, periods, aob,
                                         Opart, Mpart, Lpart);
    // 2b) merge chunks for P==1 slots
    reduce_p1<<<dim3(16, BATCH * NHEAD), 256, 0, stream>>>(
        periods, Opart, Mpart, Lpart, aob);

    // 3) out projection (bf16 MFMA, fp32 weights)
    dim3 g3(M_ROWS / 128, D_MODEL / 128);         // 64 x 4
    out_gemm_mfma<<<g3, 256, 0, stream>>>(aob, out_w, out_b, out);
}

// Round 10
// 166.760 us; speedup vs baseline: 1.4448x; 1.0351x over previous
//
#include <hip/hip_runtime.h>
#include <math.h>

#define D_MODEL 512
#define NHEAD   8
#define HD      64
#define T_SEQ   2048
#define BATCH   4
#define M_ROWS  (BATCH * T_SEQ)   // 8192

typedef __attribute__((ext_vector_type(8))) short  short8;   // 8 bf16 = 4 VGPRs
typedef __attribute__((ext_vector_type(4))) float  floatx4;

// round-to-nearest-even fp32 -> bf16 (bit math; inputs finite)
__device__ __forceinline__ unsigned short f2bf(float f) {
    unsigned int u = __float_as_uint(f);
    unsigned int r = u + 0x7FFFu + ((u >> 16) & 1u);
    return (unsigned short)(r >> 16);
}

__device__ __forceinline__ float bf2f(unsigned short u) {
    return __uint_as_float((unsigned int)u << 16);
}

// pack 8 fp32 -> 8 bf16 in an int4
__device__ __forceinline__ int4 cvt8(float4 a, float4 b) {
    union { unsigned short u[8]; int4 v; } r;
    r.u[0] = f2bf(a.x); r.u[1] = f2bf(a.y); r.u[2] = f2bf(a.z); r.u[3] = f2bf(a.w);
    r.u[4] = f2bf(b.x); r.u[5] = f2bf(b.y); r.u[6] = f2bf(b.z); r.u[7] = f2bf(b.w);
    return r.v;
}

// decompose tile-slot t for head period P: residue r, q-tile mt, subseq len Lr.
// returns false if t is out of range.
__device__ __forceinline__ bool slot_decode(int t, int P, int& r, int& mt, int& Lr)
{
    const int q0 = T_SEQ / P, rem = T_SEQ % P;
    const int nt_hi = (q0 + 64) >> 6;
    const int nt_lo = (q0 + 63) >> 6;
    const int hi_total = rem * nt_hi;
    if (t < hi_total) {
        r = t / nt_hi; mt = t - r * nt_hi; Lr = q0 + 1;
    } else {
        t -= hi_total;
        if (t >= (P - rem) * nt_lo) return false;
        const int rr = t / nt_lo;
        r = rem + rr; mt = t - rr * nt_lo; Lr = q0;
    }
    return true;
}

// ---------------------------------------------------------------------------
// Kernel 1: QKV projection, bf16 MFMA, fp32 inputs converted at staging.
// ---------------------------------------------------------------------------
__global__ __launch_bounds__(256) void qkv_gemm_mfma(
    const float* __restrict__ X,    // 8192 x 512 fp32
    const float* __restrict__ W,    // 1536 x 512 fp32
    const float* __restrict__ bias,
    unsigned short* __restrict__ qo, unsigned short* __restrict__ ko,
    unsigned short* __restrict__ vo)
{
    __shared__ unsigned short smem[128 * 128];    // 32 KB: As|Bs, then C-tile
    unsigned short* const As = smem;              // 128 x 64
    unsigned short* const Bs = smem + 128 * 64;   // 128 x 64

    const int bid  = blockIdx.x;
    const int xcd  = bid & 7;
    const int chk_ = bid >> 3;                            // 0..95
    const int row0 = (((chk_ / 12) << 3) + xcd) << 7;
    const int col0 = (chk_ % 12) << 7;

    const int tid  = threadIdx.x;
    const int wave = tid >> 6, lane = tid & 63;
    const int quad = lane >> 4, l15 = lane & 15;
    const int wm   = wave >> 1, wn = wave & 1;
    const int lr8  = lane >> 3;
    const int sc   = lane & 7;

    floatx4 acc[4][4] = {};

    for (int k0 = 0; k0 < D_MODEL; k0 += 64) {
        int4 av[4], bv[4];
#pragma unroll
        for (int i = 0; i < 4; ++i) {
            const int r = wave * 32 + i * 8 + lr8;
            const float* ap = X + (size_t)(row0 + r) * D_MODEL + k0 + (sc << 3);
            const float* bp = W + (size_t)(col0 + r) * D_MODEL + k0 + (sc << 3);
            av[i] = cvt8(*(const float4*)ap, *(const float4*)(ap + 4));
            bv[i] = cvt8(*(const float4*)bp, *(const float4*)(bp + 4));
        }
        __syncthreads();
#pragma unroll
        for (int i = 0; i < 4; ++i) {
            const int r  = wave * 32 + i * 8 + lr8;
            const int cp = (sc ^ (r & 7)) << 3;
            *(int4*)(As + (r << 6) + cp) = av[i];
            *(int4*)(Bs + (r << 6) + cp) = bv[i];
        }
        __syncthreads();

#pragma unroll
        for (int ks = 0; ks < 2; ++ks) {
            short8 af[4], bfr[4];
            const int ch = (ks << 2) + quad;
#pragma unroll
            for (int mt = 0; mt < 4; ++mt) {
                const int row = (wm << 6) + (mt << 4) + l15;
                af[mt] = *(const short8*)(As + (row << 6) + ((ch ^ (row & 7)) << 3));
            }
#pragma unroll
            for (int nt = 0; nt < 4; ++nt) {
                const int col = (wn << 6) + (nt << 4) + l15;
                bfr[nt] = *(const short8*)(Bs + (col << 6) + ((ch ^ (col & 7)) << 3));
            }
#pragma unroll
            for (int mt = 0; mt < 4; ++mt)
#pragma unroll
                for (int nt = 0; nt < 4; ++nt)
                    acc[mt][nt] = __builtin_amdgcn_mfma_f32_16x16x32_bf16(
                        af[mt], bfr[nt], acc[mt][nt], 0, 0, 0);
        }
    }

    __syncthreads();
#pragma unroll
    for (int nt = 0; nt < 4; ++nt) {
        const int ncol = (wn << 6) + (nt << 4) + l15;
        const float bn = bias[col0 + ncol];
#pragma unroll
        for (int mt = 0; mt < 4; ++mt)
#pragma unroll
            for (int reg = 0; reg < 4; ++reg) {
                const int mrow = (wm << 6) + (mt << 4) + (quad << 2) + reg;
                smem[(mrow << 7) + ncol] = f2bf(acc[mt][nt][reg] + bn);
            }
    }
    __syncthreads();
    {
        const int c16  = lane & 15;
        const int rsub = lane >> 4;
        const int n0   = col0 + (c16 << 3);
        const int part = n0 >> 9;
        unsigned short* dst = (part == 0) ? qo : ((part == 1) ? ko : vo);
        const int head = (n0 & 511) >> 6, d0 = n0 & 63;
#pragma unroll
        for (int p = 0; p < 8; ++p) {
            const int ml = (wave << 5) + (p << 2) + rsub;
            const int m  = row0 + ml;
            const int b = m >> 11, t = m & 2047;
            int4 val = *(const int4*)(smem + (ml << 7) + (c16 << 3));
            *(int4*)(dst + ((((size_t)b << 3) + head) * T_SEQ + t) * HD + d0) = val;
        }
    }
}

// ---------------------------------------------------------------------------
// Kernel 2: residue-class flash attention, bf16 MFMA, split-K (chunks of 8
// k-tiles, up to 4 chunks/slot) + double-buffered K/V, one barrier per tile.
// Slots with mt<8 write final output directly; others write unnormalized
// partials (O, m, l) indexed by (bh, t, chunk), merged by reduce_rc.
// ---------------------------------------------------------------------------
__global__ __launch_bounds__(256) void attn_rc_mfma(
    const unsigned short* __restrict__ q, const unsigned short* __restrict__ k,
    const unsigned short* __restrict__ v, const int* __restrict__ periods,
    unsigned short* __restrict__ o,
    unsigned short* __restrict__ Opart, float* __restrict__ Mpart,
    float* __restrict__ Lpart)
{
    __shared__ unsigned short Ks[2][64 * 64];   // [key][hd]; [0] = epilogue scratch
    __shared__ unsigned short Vt[2][64 * 64];   // [hd][key]
    __shared__ unsigned short Ps[64 * 64];      // Q tile, then P̃ [q][key]

    const int bh = blockIdx.y;
    int P = periods[bh]; if (P < 1) P = 1;
    const int t_orig = blockIdx.x;
    const int c = blockIdx.z;
    int r, mt, Lr;
    if (!slot_decode(t_orig, P, r, mt, Lr)) return;
    if ((c << 3) > mt) return;                  // chunk beyond this slot
    const int nch  = (mt >> 3) + 1;
    const int kt0  = c << 3;
    const int kend = (kt0 + 7 < mt) ? (kt0 + 7) : mt;
    const int m0 = mt << 6;

    const int tid  = threadIdx.x;
    const int wave = tid >> 6, lane = tid & 63;
    const int quad = lane >> 4, l15 = lane & 15;
    const int srow = tid >> 2;                 // K/Q staging row 0..63
    const int vkp  = tid & 31, vhg = tid >> 5; // V staging

    const unsigned short* hq = q + (size_t)bh * T_SEQ * HD;
    const unsigned short* hk = k + (size_t)bh * T_SEQ * HD;
    const unsigned short* hv = v + (size_t)bh * T_SEQ * HD;

    const short8 vone = {16256, 16256, 16256, 16256,
                         16256, 16256, 16256, 16256};   // bf16 1.0 x8

    // ---- stage Q tile into Ps + first K/V tile into buf 0, one barrier ----
    {
        int m = m0 + srow; if (m > Lr - 1) m = Lr - 1;
        const unsigned short* src = hq + (size_t)(r + m * P) * HD;
#pragma unroll
        for (int rep = 0; rep < 2; ++rep) {
            const int cc = ((tid & 3) << 1) + rep;
            int4 a = *(const int4*)(src + (cc << 3));
            *(int4*)(Ps + (srow << 6) + ((cc ^ (srow & 7)) << 3)) = a;
        }
    }
    {
        const int km0 = kt0 << 6;
        int mk = km0 + srow; if (mk > Lr - 1) mk = Lr - 1;
        const unsigned short* ksrc = hk + (size_t)(r + mk * P) * HD;
#pragma unroll
        for (int rep = 0; rep < 2; ++rep) {
            const int cc = ((tid & 3) << 1) + rep;
            int4 a = *(const int4*)(ksrc + (cc << 3));
            *(int4*)(Ks[0] + (srow << 6) + ((cc ^ (srow & 7)) << 3)) = a;
        }
        int mv0 = km0 + (vkp << 1);     if (mv0 > Lr - 1) mv0 = Lr - 1;
        int mv1 = km0 + (vkp << 1) + 1; if (mv1 > Lr - 1) mv1 = Lr - 1;
        int4 va = *(const int4*)(hv + (size_t)(r + mv0 * P) * HD + (vhg << 3));
        int4 vb = *(const int4*)(hv + (size_t)(r + mv1 * P) * HD + (vhg << 3));
        const unsigned short* pa = (const unsigned short*)&va;
        const unsigned short* pb = (const unsigned short*)&vb;
#pragma unroll
        for (int j = 0; j < 8; ++j) {
            const int hd_ = (vhg << 3) + j;
            const unsigned int pk =
                (unsigned int)pa[j] | ((unsigned int)pb[j] << 16);
            *(unsigned int*)((char*)Vt[0] + (hd_ << 7) +
                             ((((vkp >> 2) ^ (hd_ & 7)) << 4)) +
                             ((vkp & 3) << 2)) = pk;
        }
    }
    __syncthreads();
    short8 qf[2];
#pragma unroll
    for (int ks = 0; ks < 2; ++ks) {
        const int row = (wave << 4) + l15;
        qf[ks] = *(const short8*)(Ps + (row << 6) +
                                  ((((ks << 2) + quad) ^ (row & 7)) << 3));
    }

    floatx4 Oa[4] = {};
    float m_i[4] = {-1e30f, -1e30f, -1e30f, -1e30f};
    float l_i[4] = {0.f, 0.f, 0.f, 0.f};

    for (int kt = kt0; kt <= kend; ++kt) {
        const int buf = (kt - kt0) & 1;
        const bool havenext = kt < kend;

        int4 ka[2], va, vb;
        if (havenext) {
            const int km0 = (kt + 1) << 6;
            int mk = km0 + srow; if (mk > Lr - 1) mk = Lr - 1;
            const unsigned short* ksrc = hk + (size_t)(r + mk * P) * HD;
#pragma unroll
            for (int rep = 0; rep < 2; ++rep)
                ka[rep] = *(const int4*)(ksrc + ((((tid & 3) << 1) + rep) << 3));
            int mv0 = km0 + (vkp << 1);     if (mv0 > Lr - 1) mv0 = Lr - 1;
            int mv1 = km0 + (vkp << 1) + 1; if (mv1 > Lr - 1) mv1 = Lr - 1;
            va = *(const int4*)(hv + (size_t)(r + mv0 * P) * HD + (vhg << 3));
            vb = *(const int4*)(hv + (size_t)(r + mv1 * P) * HD + (vhg << 3));
        }

        // ---- QK^T from Ks[buf] ----
        floatx4 sacc[4] = {};
#pragma unroll
        for (int nt = 0; nt < 4; ++nt) {
            const int row = (nt << 4) + l15;
#pragma unroll
            for (int ks = 0; ks < 2; ++ks) {
                short8 kf = *(const short8*)(Ks[buf] + (row << 6) +
                                             ((((ks << 2) + quad) ^ (row & 7)) << 3));
                sacc[nt] = __builtin_amdgcn_mfma_f32_16x16x32_bf16(
                    qf[ks], kf, sacc[nt], 0, 0, 0);
            }
        }

        // ---- scale + causal mask; wave-wide tile max ----
        const bool diag = (kt == mt);
        float s[4][4];
        float tm = -1e30f;
#pragma unroll
        for (int nt = 0; nt < 4; ++nt)
#pragma unroll
            for (int reg = 0; reg < 4; ++reg) {
                float sv = sacc[nt][reg] * 0.125f;
                if (diag) {
                    const int sq = (wave << 4) + (quad << 2) + reg;
                    if (((nt << 4) + l15) > sq) sv = -1e30f;
                }
                s[nt][reg] = sv;
                tm = fmaxf(tm, sv);
            }
        tm = fmaxf(tm, __shfl_xor(tm, 1));
        tm = fmaxf(tm, __shfl_xor(tm, 2));
        tm = fmaxf(tm, __shfl_xor(tm, 4));
        tm = fmaxf(tm, __shfl_xor(tm, 8));
        tm = fmaxf(tm, __shfl_xor(tm, 16));
        tm = fmaxf(tm, __shfl_xor(tm, 32));

        float sc[4];
#pragma unroll
        for (int reg = 0; reg < 4; ++reg) {
            const float nm = fmaxf(m_i[reg], tm);
            sc[reg] = __expf(m_i[reg] - nm);
            m_i[reg] = nm;
        }

        // ---- P̃ -> Ps (own-wave rows) ----
#pragma unroll
        for (int reg = 0; reg < 4; ++reg) {
            const int row = (wave << 4) + (quad << 2) + reg;
#pragma unroll
            for (int nt = 0; nt < 4; ++nt) {
                const int col = (nt << 4) + l15;
                *((unsigned short*)((char*)Ps + (row << 7) +
                                    (((col >> 3) ^ (row & 7)) << 4) +
                                    ((col & 7) << 1))) =
                    f2bf(__expf(s[nt][reg] - m_i[reg]));
            }
        }

        // ---- pf reads; row sums via MFMA(ones); l update ----
        short8 pf[2];
#pragma unroll
        for (int ks = 0; ks < 2; ++ks) {
            const int row = (wave << 4) + l15;
            pf[ks] = *(const short8*)(Ps + (row << 6) +
                                      ((((ks << 2) + quad) ^ (row & 7)) << 3));
        }
        floatx4 ls = {};
        ls = __builtin_amdgcn_mfma_f32_16x16x32_bf16(pf[0], vone, ls, 0, 0, 0);
        ls = __builtin_amdgcn_mfma_f32_16x16x32_bf16(pf[1], vone, ls, 0, 0, 0);
#pragma unroll
        for (int reg = 0; reg < 4; ++reg)
            l_i[reg] = l_i[reg] * sc[reg] + ls[reg];

        // ---- PV from Vt[buf] ----
#pragma unroll
        for (int nt = 0; nt < 4; ++nt)
#pragma unroll
            for (int reg = 0; reg < 4; ++reg)
                Oa[nt][reg] *= sc[reg];
#pragma unroll
        for (int nt = 0; nt < 4; ++nt) {
            const int row = (nt << 4) + l15;
#pragma unroll
            for (int ks = 0; ks < 2; ++ks) {
                short8 vf = *(const short8*)(Vt[buf] + (row << 6) +
                                             ((((ks << 2) + quad) ^ (row & 7)) << 3));
                Oa[nt] = __builtin_amdgcn_mfma_f32_16x16x32_bf16(
                    pf[ks], vf, Oa[nt], 0, 0, 0);
            }
        }

        // ---- stage next tile into the other buffer; ONE barrier ----
        if (havenext) {
#pragma unroll
            for (int rep = 0; rep < 2; ++rep) {
                const int cc = ((tid & 3) << 1) + rep;
                *(int4*)(Ks[buf ^ 1] + (srow << 6) + ((cc ^ (srow & 7)) << 3)) = ka[rep];
            }
            const unsigned short* pa = (const unsigned short*)&va;
            const unsigned short* pb = (const unsigned short*)&vb;
#pragma unroll
            for (int j = 0; j < 8; ++j) {
                const int hd_ = (vhg << 3) + j;
                const unsigned int pk =
                    (unsigned int)pa[j] | ((unsigned int)pb[j] << 16);
                *(unsigned int*)((char*)Vt[buf ^ 1] + (hd_ << 7) +
                                 ((((vkp >> 2) ^ (hd_ & 7)) << 4)) +
                                 ((vkp & 3) << 2)) = pk;
            }
        }
        __syncthreads();
    }

    if (nch == 1) {
        // ---- direct epilogue: normalize + scatter via LDS (Ks[0] scratch) ----
#pragma unroll
        for (int reg = 0; reg < 4; ++reg) {
            const float invl = 1.f / l_i[reg];
            const int row = (wave << 4) + (quad << 2) + reg;
#pragma unroll
            for (int nt = 0; nt < 4; ++nt)
                Ks[0][(row << 6) + (nt << 4) + l15] = f2bf(Oa[nt][reg] * invl);
        }
        const int lrow = lane >> 2;
        const int chk  = (lane & 3) << 1;
        const int ml   = (wave << 4) + lrow;
        const int m    = m0 + ml;
        if (m < Lr) {
            const size_t base = ((size_t)bh * T_SEQ + (r + m * P)) * HD;
            int4 w0 = *(const int4*)(Ks[0] + (ml << 6) + (chk << 3));
            int4 w1 = *(const int4*)(Ks[0] + (ml << 6) + ((chk + 1) << 3));
            *(int4*)(o + base + (chk << 3))       = w0;
            *(int4*)(o + base + ((chk + 1) << 3)) = w1;
        }
    } else {
        // ---- partial epilogue: unnormalized O + (m,l), slot=(bh,t,chunk) ----
        const size_t slot = ((size_t)((bh << 6) + t_orig) << 2) + c;
#pragma unroll
        for (int reg = 0; reg < 4; ++reg) {
            const int row = (wave << 4) + (quad << 2) + reg;
#pragma unroll
            for (int nt = 0; nt < 4; ++nt)
                Ks[0][(row << 6) + (nt << 4) + l15] = f2bf(Oa[nt][reg]);
            if (l15 == 0) {
                Mpart[slot * 64 + row] = m_i[reg];
                Lpart[slot * 64 + row] = l_i[reg];
            }
        }
        const int lrow = lane >> 2;
        const int chk  = (lane & 3) << 1;
        const int ml   = (wave << 4) + lrow;
        unsigned short* dst = Opart + slot * 4096 + (ml << 6);
        *(int4*)(dst + (chk << 3))       = *(const int4*)(Ks[0] + (ml << 6) + (chk << 3));
        *(int4*)(dst + ((chk + 1) << 3)) = *(const int4*)(Ks[0] + (ml << 6) + ((chk + 1) << 3));
    }
}

// ---------------------------------------------------------------------------
// Kernel 2b: merge 2..4 chunks of multi-chunk slots (mt >= 8).
// ---------------------------------------------------------------------------
__global__ __launch_bounds__(256) void reduce_rc(
    const int* __restrict__ periods,
    const unsigned short* __restrict__ Opart, const float* __restrict__ Mpart,
    const float* __restrict__ Lpart, unsigned short* __restrict__ o)
{
    const int bh = blockIdx.y;
    int P = periods[bh]; if (P < 1) P = 1;
    const int t = blockIdx.x;
    int r, mt, Lr;
    if (!slot_decode(t, P, r, mt, Lr)) return;
    const int nch = (mt >> 3) + 1;
    if (nch < 2) return;

    const int tid = threadIdx.x;
    const int row = tid >> 2;
    const int cg  = (tid & 3) << 4;             // 16 cols per thread
    const int m   = (mt << 6) + row;
    if (m >= Lr) return;

    const size_t slot0 = (size_t)((bh << 6) + t) << 2;

    float mv[4], lv[4];
    float mm = -1e30f;
    for (int cc = 0; cc < nch; ++cc) {
        mv[cc] = Mpart[(slot0 + cc) * 64 + row];
        lv[cc] = Lpart[(slot0 + cc) * 64 + row];
        mm = fmaxf(mm, mv[cc]);
    }
    float lsum = 0.f, a[4];
    for (int cc = 0; cc < nch; ++cc) {
        a[cc] = __expf(mv[cc] - mm);
        lsum += a[cc] * lv[cc];
    }
    const float inv = 1.f / lsum;

    float ov[16] = {};
    for (int cc = 0; cc < nch; ++cc) {
        const unsigned short* p = Opart + (slot0 + cc) * 4096 + (row << 6) + cg;
        const float ac = a[cc];
#pragma unroll
        for (int j = 0; j < 16; ++j) ov[j] += ac * bf2f(p[j]);
    }
    unsigned short outv[16];
#pragma unroll
    for (int j = 0; j < 16; ++j) outv[j] = f2bf(ov[j] * inv);

    unsigned short* dst = o + ((size_t)bh * T_SEQ + (r + m * P)) * HD + cg;
    *(int4*)dst       = *(const int4*)&outv[0];
    *(int4*)(dst + 8) = *(const int4*)&outv[8];
}

// ---------------------------------------------------------------------------
// Kernel 3: out projection, bf16 MFMA; A head-major bf16, W fp32 converted
// at staging.
// ---------------------------------------------------------------------------
__global__ __launch_bounds__(256) void out_gemm_mfma(
    const unsigned short* __restrict__ A,
    const float* __restrict__ W,            // 512 x 512 fp32
    const float* __restrict__ bias,
    float* __restrict__ out)
{
    __shared__ unsigned short As[128 * 64];
    __shared__ unsigned short Bs[128 * 64];

    const int tid  = threadIdx.x;
    const int wave = tid >> 6, lane = tid & 63;
    const int quad = lane >> 4, l15 = lane & 15;
    const int wm   = wave >> 1, wn = wave & 1;
    const int row0 = blockIdx.x * 128;
    const int col0 = blockIdx.y * 128;
    const int lr8  = lane >> 3;
    const int sc   = lane & 7;

    floatx4 acc[4][4] = {};

    for (int k0 = 0; k0 < D_MODEL; k0 += 64) {
        const int h = k0 >> 6;
        int4 av[4], bv[4];
#pragma unroll
        for (int i = 0; i < 4; ++i) {
            const int r  = wave * 32 + i * 8 + lr8;
            const int rg = row0 + r;
            const int b = rg >> 11, t = rg & 2047;
            av[i] = *(const int4*)(A + ((((size_t)b << 3) + h) * T_SEQ + t) * HD + (sc << 3));
            const float* bp = W + (size_t)(col0 + r) * D_MODEL + k0 + (sc << 3);
            bv[i] = cvt8(*(const float4*)bp, *(const float4*)(bp + 4));
        }
        __syncthreads();
#pragma unroll
        for (int i = 0; i < 4; ++i) {
            const int r  = wave * 32 + i * 8 + lr8;
            const int cp = (sc ^ (r & 7)) << 3;
            *(int4*)(As + (r << 6) + cp) = av[i];
            *(int4*)(Bs + (r << 6) + cp) = bv[i];
        }
        __syncthreads();

#pragma unroll
        for (int ks = 0; ks < 2; ++ks) {
            short8 af[4], bfr[4];
            const int ch = (ks << 2) + quad;
#pragma unroll
            for (int mt = 0; mt < 4; ++mt) {
                const int row = (wm << 6) + (mt << 4) + l15;
                af[mt] = *(const short8*)(As + (row << 6) + ((ch ^ (row & 7)) << 3));
            }
#pragma unroll
            for (int nt = 0; nt < 4; ++nt) {
                const int col = (wn << 6) + (nt << 4) + l15;
                bfr[nt] = *(const short8*)(Bs + (col << 6) + ((ch ^ (col & 7)) << 3));
            }
#pragma unroll
            for (int mt = 0; mt < 4; ++mt)
#pragma unroll
                for (int nt = 0; nt < 4; ++nt)
                    acc[mt][nt] = __builtin_amdgcn_mfma_f32_16x16x32_bf16(
                        af[mt], bfr[nt], acc[mt][nt], 0, 0, 0);
        }
    }

#pragma unroll
    for (int nt = 0; nt < 4; ++nt) {
        const int n = col0 + (wn << 6) + (nt << 4) + l15;
        const float bn = bias[n];
#pragma unroll
        for (int mt = 0; mt < 4; ++mt) {
#pragma unroll
            for (int reg = 0; reg < 4; ++reg) {
                const int m = row0 + (wm << 6) + (mt << 4) + (quad << 2) + reg;
                out[(size_t)m * D_MODEL + n] = acc[mt][nt][reg] + bn;
            }
        }
    }
}

// ---------------------------------------------------------------------------
extern "C" void kernel_launch(void* const* d_in, const int* in_sizes, int n_in,
                              void* d_out, int out_size, void* d_ws, size_t ws_size,
                              hipStream_t stream)
{
    const float* x        = (const float*)d_in[0];
    const int*   periods  = (const int*)  d_in[1];
    const float* in_w     = (const float*)d_in[2];
    const float* in_b     = (const float*)d_in[3];
    const float* out_w    = (const float*)d_in[4];
    const float* out_b    = (const float*)d_in[5];
    float*       out      = (float*)d_out;

    const size_t TENS = (size_t)BATCH * NHEAD * T_SEQ * HD;   // 4,194,304
    unsigned short* qb    = (unsigned short*)d_ws;
    unsigned short* kb    = qb + TENS;
    unsigned short* vb    = kb + TENS;
    unsigned short* aob   = vb + TENS;
    unsigned short* Opart = aob + TENS;                // 8192 slots x 4096 bf16
    float*          Mpart = (float*)(Opart + (size_t)8192 * 4096);
    float*          Lpart = Mpart + (size_t)8192 * 64;
    // ws usage: 4*8.4MB + 67MB + 2MB + 2MB ~= 104 MB (ws_size = 256 MiB)

    // 1) QKV projection (bf16 MFMA, fp32 inputs), XCD-swizzled flat grid
    qkv_gemm_mfma<<<(M_ROWS / 128) * ((3 * D_MODEL) / 128), 256, 0, stream>>>(
        x, in_w, in_b, qb, kb, vb);

    // 2) residue-class flash attention, split-K chunks of 8 k-tiles
    dim3 g2(64, BATCH * NHEAD, 4);
    attn_rc_mfma<<<g2, 256, 0, stream>>>(qb, kb, vb, periods, aob,
                                         Opart, Mpart, Lpart);
    // 2b) merge chunks (slots with mt >= 8)
    reduce_rc<<<dim3(64, BATCH * NHEAD), 256, 0, stream>>>(
        periods, Opart, Mpart, Lpart, aob);

    // 3) out projection (bf16 MFMA, fp32 weights)
    dim3 g3(M_ROWS / 128, D_MODEL / 128);         // 64 x 4
    out_gemm_mfma<<<g3, 256, 0, stream>>>(aob, out_w, out_b, out);
}